// Round 11
// baseline (98.620 us; speedup 1.0000x reference)
//
#include <hip/hip_runtime.h>
#include <hip/hip_bf16.h>
#include <stdint.h>

#define MDIM 16384
#define NDIM 1024
#define KDIM 1024
#define BM 256
#define BN 256
#define BK 64
#define NT (KDIM / BK)   // 16 K-tiles

typedef __bf16 bf16x8 __attribute__((ext_vector_type(8)));
typedef float f32x4 __attribute__((ext_vector_type(4)));
typedef uint  u32x4 __attribute__((ext_vector_type(4)));

#define GLOBAL_CPTR(p) ((const __attribute__((address_space(1))) void*)(p))
#define LDS_PTR(p)     ((__attribute__((address_space(3))) void*)(p))

// ---------------- fp32 -> bf16 (RNE) convert (used for W only) --------------
__device__ inline ushort f2bf_rne(float f) {
    union { float f; uint32_t u; } c; c.f = f;
    uint32_t u = c.u;
    return (ushort)((u + 0x7fffu + ((u >> 16) & 1u)) >> 16);
}

__global__ __launch_bounds__(256) void cvt_f32_bf16(const float* __restrict__ src,
                                                    ushort* __restrict__ dst, int n8) {
    int i = blockIdx.x * 256 + threadIdx.x;
    if (i >= n8) return;
    const float4* s4 = (const float4*)src;
    float4 a = s4[2 * i];
    float4 b = s4[2 * i + 1];
    union { ushort us[8]; uint4 u4; } p;
    p.us[0] = f2bf_rne(a.x); p.us[1] = f2bf_rne(a.y);
    p.us[2] = f2bf_rne(a.z); p.us[3] = f2bf_rne(a.w);
    p.us[4] = f2bf_rne(b.x); p.us[5] = f2bf_rne(b.y);
    p.us[6] = f2bf_rne(b.z); p.us[7] = f2bf_rne(b.w);
    ((uint4*)dst)[i] = p.u4;
}

__device__ inline uint pk2bf(float lo, float hi) {
    union { __hip_bfloat162 h2; uint u; } c;
    c.h2 = __float22bfloat162_rn(float2{lo, hi});
    return c.u;
}

// ---------------- R7 structure, templated for ablation -----------------------
// V=0: full kernel (R7 gemm_1b exact).  V=1: noMFMA ablation — identical
// memory path (ds_reads kept live via empty asm, full staging/cvt/waits/
// barriers), MFMA removed.  REP: K-loop repetition (k-index wraps mod NT)
// to control dispatch duration without changing the per-block regime.
template<int V, int REP>
__global__ __launch_bounds__(512, 2) void gemm_abl(const float* __restrict__ A,
                                                   const ushort* __restrict__ B,
                                                   const float* __restrict__ bias,
                                                   float* __restrict__ C) {
    __shared__ ushort As[2][BM * BK];   // 2 x 32 KiB
    __shared__ ushort Bs[2][BN * BK];   // 2 x 32 KiB

    const int tid  = threadIdx.x;
    const int lane = tid & 63;
    const int wave = tid >> 6;
    const int wr   = wave >> 2;   // 0..1 : M half (128 rows)
    const int wc   = wave & 3;    // 0..3 : N quarter (64 cols)
    const int l15  = lane & 15;
    const int l4   = lane >> 4;

    // T1: chunked XCD swizzle (bijective, 256 blocks % 8 == 0)
    const int lin  = blockIdx.y * gridDim.x + blockIdx.x;   // 0..255
    const int swz  = (lin & 7) * 32 + (lin >> 3);
    const int brow = (swz >> 2) * BM;
    const int bcol = (swz & 3) * BN;

    // ---- A staging geometry (512 threads cover 256x64 fp32 in 8 GLD4)
    const int lrow = tid >> 3;           // 0..63
    const int lcb  = (tid & 7) * 16;     // byte col (pre-swizzle) in bf16 row
    const int swb  = (lrow & 7) << 4;
    const int wb0  = lrow * 128 + (lcb ^ swb);   // swizzled ds_write byte off
    const float* Ag = A + (size_t)(brow + lrow) * KDIM + (tid & 7) * 8;

    // ---- B staging: global_load_lds linear dest, inverse-swizzled source
    const ushort* Bsrc = B + (size_t)(bcol + lrow) * KDIM + ((lcb ^ swb) >> 1);

    // ---- fragment ds_read byte offsets (swizzled)
    const int sw   = (l15 & 7) << 4;
    const int off0 = l15 * 128 + ((l4 * 16) ^ sw);
    const int off1 = l15 * 128 + (((l4 * 16) + 64) ^ sw);

#define BARRIER __builtin_amdgcn_s_barrier()
#define LGKM0  asm volatile("s_waitcnt lgkmcnt(0)" ::: "memory")
#define VMC(n) asm volatile("s_waitcnt vmcnt(" #n ")" ::: "memory")
#define SCHED0 __builtin_amdgcn_sched_barrier(0)
#define GLD4(d, p) asm volatile("global_load_dwordx4 %0, %1, off" : "=v"(d) : "v"(p) : "memory")
#define KEEP2(x, y) asm volatile("" :: "v"(x), "v"(y))

    // B tile 256x64 bf16 = 32 KiB staged in 4 global_load_lds issues
#define STG_B4(bb, t_) do { _Pragma("unroll") \
    for (int s_ = 0; s_ < 4; ++s_) \
        __builtin_amdgcn_global_load_lds( \
            GLOBAL_CPTR(Bsrc + (size_t)(s_ * 64) * KDIM + (t_) * BK), \
            LDS_PTR(&Bs[bb][s_ * 4096 + tid * 8]), 16, 0, 0); } while (0)

    // issue all 8 A-loads (256 rows x BK fp32) for K-tile t_ into ar[0..7]
#define GLDA_T(t_) do { \
    const float* q_ = Ag + (size_t)(t_) * BK; \
    GLD4(ar[0], q_);                       GLD4(ar[1], q_ + 4); \
    GLD4(ar[2], q_ + (size_t) 64 * KDIM);  GLD4(ar[3], q_ + (size_t) 64 * KDIM + 4); \
    GLD4(ar[4], q_ + (size_t)128 * KDIM);  GLD4(ar[5], q_ + (size_t)128 * KDIM + 4); \
    GLD4(ar[6], q_ + (size_t)192 * KDIM);  GLD4(ar[7], q_ + (size_t)192 * KDIM + 4); } while (0)

    // convert ar[0..7] and ds_write (swizzled) the full 256-row A tile
#define CVTW_T(bb) do { _Pragma("unroll") \
    for (int h_ = 0; h_ < 4; ++h_) { \
        u32x4 k_; \
        k_.x = pk2bf(ar[2*h_].x, ar[2*h_].y); k_.y = pk2bf(ar[2*h_].z, ar[2*h_].w); \
        k_.z = pk2bf(ar[2*h_+1].x, ar[2*h_+1].y); k_.w = pk2bf(ar[2*h_+1].z, ar[2*h_+1].w); \
        *(u32x4*)((char*)&As[bb][0] + h_ * 64 * 128 + wb0) = k_; } } while (0)

    // ds_read one A m-half (8 x b128) into af
#define LOAD_A(bb, mh) do { _Pragma("unroll") \
    for (int i_ = 0; i_ < 4; ++i_) { \
        const char* pb_ = (const char*)&As[bb][0] + (wr * 128 + (mh) * 64 + i_ * 16) * 128; \
        af[i_][0] = *(const bf16x8*)(pb_ + off0); \
        af[i_][1] = *(const bf16x8*)(pb_ + off1); } } while (0)

    // ds_read ALL B frags (both n-halves, 8 x b128) into bfr
#define LOAD_B_ALL(bb) do { _Pragma("unroll") \
    for (int nh_ = 0; nh_ < 2; ++nh_) { _Pragma("unroll") \
        for (int j_ = 0; j_ < 2; ++j_) { \
            const char* pb_ = (const char*)&Bs[bb][0] + (wc * 64 + nh_ * 32 + j_ * 16) * 128; \
            bfr[nh_][j_][0] = *(const bf16x8*)(pb_ + off0); \
            bfr[nh_][j_][1] = *(const bf16x8*)(pb_ + off1); } } } while (0)

    // keep freshly-loaded frags live without MFMA (rule #17: anti-DCE)
#define KEEP_A do { _Pragma("unroll") \
    for (int i_ = 0; i_ < 4; ++i_) KEEP2(af[i_][0], af[i_][1]); } while (0)
#define KEEP_B do { _Pragma("unroll") \
    for (int nh_ = 0; nh_ < 2; ++nh_) { _Pragma("unroll") \
        for (int j_ = 0; j_ < 2; ++j_) KEEP2(bfr[nh_][j_][0], bfr[nh_][j_][1]); } } while (0)

    // 32 MFMA: both n-halves for m-half mh
#define MFMA_H(mh) do { __builtin_amdgcn_s_setprio(1); _Pragma("unroll") \
    for (int i_ = 0; i_ < 4; ++i_) { _Pragma("unroll") \
        for (int nh_ = 0; nh_ < 2; ++nh_) { _Pragma("unroll") \
            for (int j_ = 0; j_ < 2; ++j_) { _Pragma("unroll") \
                for (int kk_ = 0; kk_ < 2; ++kk_) \
                    acc[(mh)*4 + i_][nh_*2 + j_] = __builtin_amdgcn_mfma_f32_16x16x32_bf16( \
                        af[i_][kk_], bfr[nh_][j_][kk_], \
                        acc[(mh)*4 + i_][nh_*2 + j_], 0, 0, 0); } } } \
    __builtin_amdgcn_s_setprio(0); } while (0)

    f32x4  acc[8][4] = {};   // 128 AGPR
    bf16x8 af[4][2];         // 32 VGPR  A frags (current m-half, reloaded)
    bf16x8 bfr[2][2][2];     // 32 VGPR  B frags (whole tile)
    f32x4  ar[8];            // 32 VGPR  A reg-staging

    // ---- prologue: As[0]/Bs[0] staged; leave A(1)x8 in flight.
    GLDA_T(0);                 // A0 x8
    STG_B4(0, 0);              // +B0 x4 = 12
    VMC(4); SCHED0;            // retire A0 (B0 stays)
    CVTW_T(0);
    SCHED0;
    GLDA_T(1);                 // +A1 x8 -> [B0 x4, A1 x8]
    VMC(8);                    // retire B0 (A1 stays)
    LGKM0;
    BARRIER;                   // invariant: outstanding = A(u+1) x8

    // ---- main loop: ONE barrier per K-tile; all waits counted.
    const int NTT = NT * REP;
#pragma unroll 1
    for (int u = 0; u < NTT; ++u) {
        const int cur = u & 1;
        const int kn  = (u + 1) & (NT - 1);   // wrapped staging k-indices
        const int kn2 = (u + 2) & (NT - 1);
        LOAD_A(cur, 0);                          // 8 ds_read_b128
        LOAD_B_ALL(cur);                         // 8 ds_read_b128
        if constexpr (V == 0) { MFMA_H(0); }
        else                  { KEEP_A; KEEP_B; }
        LOAD_A(cur, 1);                          // 8 ds_read_b128
        if constexpr (V != 0) KEEP_A;
        if (u + 1 < NTT) {
            STG_B4(cur ^ 1, kn);                 // [A(u+1)x8, Bx4]
            VMC(4); SCHED0;                      // retire A(u+1)x8
            CVTW_T(cur ^ 1); SCHED0;             // cvt + swizzled ds_write
        }
        if (u + 2 < NTT) { GLDA_T(kn2); SCHED0; }  // [Bx4, A(u+2)x8]
        if constexpr (V == 0) { MFMA_H(1); }
        if (u + 2 < NTT)      { VMC(8); }        // retire B(u+1)x4
        else if (u + 1 < NTT) { VMC(0); }
        if (u + 1 < NTT) { LGKM0; BARRIER; }
    }

    // ---- epilogue: C = acc + bias (identical store pattern for all V)
#pragma unroll
    for (int mh = 0; mh < 2; ++mh)
#pragma unroll
        for (int i = 0; i < 4; ++i)
#pragma unroll
            for (int nh = 0; nh < 2; ++nh)
#pragma unroll
                for (int j = 0; j < 2; ++j) {
                    f32x4 v = acc[mh * 4 + i][nh * 2 + j];
                    const int row0 = brow + wr * 128 + mh * 64 + i * 16 + l4 * 4;
                    const int col  = bcol + wc * 64 + nh * 32 + j * 16 + l15;
                    const float bb2 = bias[col];
#pragma unroll
                    for (int r = 0; r < 4; ++r)
                        C[(size_t)(row0 + r) * NDIM + col] = v[r] + bb2;
                }
}

// ---------------- naive fp32 fallback (only if ws too small) ----------------
__global__ __launch_bounds__(256) void gemm_naive(const float* __restrict__ x,
                                                  const float* __restrict__ w,
                                                  const float* __restrict__ bias,
                                                  float* __restrict__ out) {
    long o = (long)blockIdx.x * 256 + threadIdx.x;
    if (o >= (long)MDIM * NDIM) return;
    int b = (int)(o / NDIM), n = (int)(o % NDIM);
    const float* xr = x + (long)b * KDIM;
    const float* wr = w + (long)n * KDIM;
    float s = 0.f;
    for (int k = 0; k < KDIM; ++k) s += xr[k] * wr[k];
    out[o] = s + bias[n];
}

extern "C" void kernel_launch(void* const* d_in, const int* in_sizes, int n_in,
                              void* d_out, int out_size, void* d_ws, size_t ws_size,
                              hipStream_t stream) {
    const float* x    = (const float*)d_in[0];
    const float* w    = (const float*)d_in[1];
    const float* bias = (const float*)d_in[2];
    float* out = (float*)d_out;

    const size_t need = (size_t)NDIM * KDIM * sizeof(ushort);   // 2 MiB (W only)
    if (ws_size >= need) {
        ushort* wb = (ushort*)d_ws;
        const int n8w = NDIM * KDIM / 8;   // 131,072
        cvt_f32_bf16<<<n8w / 256, 256, 0, stream>>>(w, wb, n8w);
        dim3 grid(NDIM / BN, MDIM / BM);   // (4, 64) = 256 blocks
        // ABLATION (noMFMA, REP=2): identical memory path, MFMA removed.
        // Writes d_out with wrong values; fully overwritten by the real
        // kernel below, so the final state is correct & deterministic.
        gemm_abl<1, 2><<<grid, 512, 0, stream>>>(x, wb, bias, out);
        // Real kernel (R7 structure): correct output.
        gemm_abl<0, 1><<<grid, 512, 0, stream>>>(x, wb, bias, out);
    } else {
        const long total = (long)MDIM * NDIM;
        gemm_naive<<<(int)((total + 255) / 256), 256, 0, stream>>>(x, w, bias, out);
    }
}

// Round 12
// 87.248 us; speedup vs baseline: 1.1303x; 1.1303x over previous
//
#include <hip/hip_runtime.h>
#include <hip/hip_bf16.h>
#include <stdint.h>

#define MDIM 16384
#define NDIM 1024
#define KDIM 1024
#define BM 256
#define BN 256
#define BK 64
#define NT (KDIM / BK)   // 16 K-tiles

typedef __bf16 bf16x8 __attribute__((ext_vector_type(8)));
typedef float f32x4 __attribute__((ext_vector_type(4)));
typedef uint  u32x4 __attribute__((ext_vector_type(4)));

#define GLOBAL_CPTR(p) ((const __attribute__((address_space(1))) void*)(p))
#define LDS_PTR(p)     ((__attribute__((address_space(3))) void*)(p))

// ---------------- fp32 -> bf16 (RNE) convert (used for W only) --------------
__device__ inline ushort f2bf_rne(float f) {
    union { float f; uint32_t u; } c; c.f = f;
    uint32_t u = c.u;
    return (ushort)((u + 0x7fffu + ((u >> 16) & 1u)) >> 16);
}

__global__ __launch_bounds__(256) void cvt_f32_bf16(const float* __restrict__ src,
                                                    ushort* __restrict__ dst, int n8) {
    int i = blockIdx.x * 256 + threadIdx.x;
    if (i >= n8) return;
    const float4* s4 = (const float4*)src;
    float4 a = s4[2 * i];
    float4 b = s4[2 * i + 1];
    union { ushort us[8]; uint4 u4; } p;
    p.us[0] = f2bf_rne(a.x); p.us[1] = f2bf_rne(a.y);
    p.us[2] = f2bf_rne(a.z); p.us[3] = f2bf_rne(a.w);
    p.us[4] = f2bf_rne(b.x); p.us[5] = f2bf_rne(b.y);
    p.us[6] = f2bf_rne(b.z); p.us[7] = f2bf_rne(b.w);
    ((uint4*)dst)[i] = p.u4;
}

__device__ inline uint pk2bf(float lo, float hi) {
    union { __hip_bfloat162 h2; uint u; } c;
    c.h2 = __float22bfloat162_rn(float2{lo, hi});
    return c.u;
}

// ---------------- producer/consumer 256x256 GEMM -----------------------------
// C = A(MxK, fp32) * B^T (B = W bf16, NxK) + bias.
// 640 threads: waves 0..7 CONSUMERS (pure ds_read+MFMA; no VMEM/asm/fences),
// waves 8..9 PRODUCERS (A: GLD4 -> cvt -> swizzled ds_write, 4-chunk pipeline
// with counted per-wave vmcnt; B: 16x global_load_lds, inverse-swizzled src).
// ONE s_barrier per K-tile; barrier counts identical across roles.
__global__ __launch_bounds__(640, 1) void gemm_pc(const float* __restrict__ A,
                                                  const ushort* __restrict__ B,
                                                  const float* __restrict__ bias,
                                                  float* __restrict__ C) {
    __shared__ ushort As[2][BM * BK];   // 2 x 32 KiB
    __shared__ ushort Bs[2][BN * BK];   // 2 x 32 KiB

    const int tid  = threadIdx.x;
    const int wave = tid >> 6;          // 0..9

    // T1: chunked XCD swizzle (bijective, 256 blocks % 8 == 0)
    const int lin  = blockIdx.y * gridDim.x + blockIdx.x;   // 0..255
    const int swz  = (lin & 7) * 32 + (lin >> 3);
    const int brow = (swz >> 2) * BM;
    const int bcol = (swz & 3) * BN;

#define BARRIER __builtin_amdgcn_s_barrier()
#define LGKM0  asm volatile("s_waitcnt lgkmcnt(0)" ::: "memory")
#define VMC(n) asm volatile("s_waitcnt vmcnt(" #n ")" ::: "memory")
#define SCHED0 __builtin_amdgcn_sched_barrier(0)
#define GLD4(d, p) asm volatile("global_load_dwordx4 %0, %1, off" : "=v"(d) : "v"(p) : "memory")

    if (wave < 8) {
        // =================== CONSUMERS ===================
        const int lane = tid & 63;
        const int wr   = wave >> 2;   // 0..1 : M half (128 rows)
        const int wc   = wave & 3;    // 0..3 : N quarter (64 cols)
        const int l15  = lane & 15;
        const int l4   = lane >> 4;
        const int sw   = (l15 & 7) << 4;
        const int off0 = l15 * 128 + ((l4 * 16) ^ sw);
        const int off1 = l15 * 128 + (((l4 * 16) + 64) ^ sw);

        f32x4  acc[8][4] = {};   // 128 AGPR
        bf16x8 bfr[2][2][2];     // 32 VGPR (whole-tile B frags)
        bf16x8 af2[2][2];        // 16 VGPR (quarter A frags)

        BARRIER;                 // tile 0 staged by producers

#pragma unroll 1
        for (int u = 0; u < NT; ++u) {
            const int cur = u & 1;
            // B frags: 8 ds_read_b128
#pragma unroll
            for (int nh = 0; nh < 2; ++nh)
#pragma unroll
                for (int j = 0; j < 2; ++j) {
                    const char* pb = (const char*)&Bs[cur][0]
                                   + (wc * 64 + nh * 32 + j * 16) * 128;
                    bfr[nh][j][0] = *(const bf16x8*)(pb + off0);
                    bfr[nh][j][1] = *(const bf16x8*)(pb + off1);
                }
            // 4 quarters: {4 ds_read_b128 + 16 MFMA} each
#pragma unroll
            for (int q = 0; q < 4; ++q) {
#pragma unroll
                for (int i2 = 0; i2 < 2; ++i2) {
                    const char* pa = (const char*)&As[cur][0]
                                   + (wr * 128 + (q * 2 + i2) * 16) * 128;
                    af2[i2][0] = *(const bf16x8*)(pa + off0);
                    af2[i2][1] = *(const bf16x8*)(pa + off1);
                }
                __builtin_amdgcn_s_setprio(1);
#pragma unroll
                for (int i2 = 0; i2 < 2; ++i2)
#pragma unroll
                    for (int nh = 0; nh < 2; ++nh)
#pragma unroll
                        for (int j = 0; j < 2; ++j)
#pragma unroll
                            for (int kk = 0; kk < 2; ++kk)
                                acc[q * 2 + i2][nh * 2 + j] =
                                    __builtin_amdgcn_mfma_f32_16x16x32_bf16(
                                        af2[i2][kk], bfr[nh][j][kk],
                                        acc[q * 2 + i2][nh * 2 + j], 0, 0, 0);
                __builtin_amdgcn_s_setprio(0);
            }
            BARRIER;
        }

        // ---- epilogue: C = acc + bias
        float bv[4];
#pragma unroll
        for (int n = 0; n < 4; ++n)
            bv[n] = bias[bcol + wc * 64 + n * 16 + l15];
#pragma unroll
        for (int m = 0; m < 8; ++m) {
            const int row0 = brow + wr * 128 + m * 16 + l4 * 4;
#pragma unroll
            for (int n = 0; n < 4; ++n) {
                const int col = bcol + wc * 64 + n * 16 + l15;
#pragma unroll
                for (int r = 0; r < 4; ++r)
                    C[(size_t)(row0 + r) * NDIM + col] = acc[m][n][r] + bv[n];
            }
        }
    } else {
        // =================== PRODUCERS ===================
        const int p     = tid - 512;         // 0..127
        const int pw    = p >> 6;            // 0..1
        const int plane = p & 63;

        // A: thread covers rows {c*64 + (p>>1)} x k-half (p&1) per chunk c
        const int prow  = p >> 1;            // 0..63
        const int pkh   = (p & 1) * 32;      // float offset within BK=64
        const float* Agp = A + (size_t)(brow + prow) * KDIM + pkh;

        // B: inverse-swizzled per-lane source; wave pw covers rows [pw*128,+128)
        const int brw   = pw * 128 + (plane >> 3);          // base row (i=0)
        const int bcb   = ((plane & 7) * 16) ^ (((plane >> 3) & 7) << 4);
        const ushort* Bgp = B + (size_t)(bcol + brw) * KDIM + (bcb >> 1);

        f32x4 arP[8], arQ[8];

        // chunk c rows: c*64 + prow ; write 32 floats -> 4 swizzled b128
#define PGLD(dst, c_, t_) do { \
    const float* q_ = Agp + (size_t)((c_) * 64) * KDIM + (t_) * BK; \
    _Pragma("unroll") \
    for (int j_ = 0; j_ < 8; ++j_) GLD4(dst[j_], q_ + 4 * j_); } while (0)

#define PCVTW(src, bb, c_) do { \
    const int rc_ = (c_) * 64 + prow; \
    char* base_ = (char*)&As[bb][0] + rc_ * 128; \
    const int swp_ = (rc_ & 7) << 4; \
    _Pragma("unroll") \
    for (int j_ = 0; j_ < 4; ++j_) { \
        u32x4 k_; \
        k_.x = pk2bf(src[2*j_].x, src[2*j_].y); \
        k_.y = pk2bf(src[2*j_].z, src[2*j_].w); \
        k_.z = pk2bf(src[2*j_+1].x, src[2*j_+1].y); \
        k_.w = pk2bf(src[2*j_+1].z, src[2*j_+1].w); \
        *(u32x4*)(base_ + (((p & 1) * 64 + j_ * 16) ^ swp_)) = k_; } } while (0)

        // 16 global_load_lds per producer wave: B tile 256x64 bf16
#define PSTG_B(bb, t_) do { _Pragma("unroll") \
    for (int i_ = 0; i_ < 16; ++i_) \
        __builtin_amdgcn_global_load_lds( \
            GLOBAL_CPTR(Bgp + (size_t)(i_ * 8) * KDIM + (t_) * BK), \
            LDS_PTR(&Bs[bb][(pw * 128 + i_ * 8) * 64 + plane * 8]), 16, 0, 0); } while (0)

        // full staging of tile t_ into buffer bb (B async + A 4-chunk pipeline)
#define PSTAGE(bb, t_) do { \
    PSTG_B(bb, t_);                    /* 16 vm ops (oldest)   */ \
    PGLD(arP, 0, t_);                  /* +8                   */ \
    PGLD(arQ, 1, t_);                  /* +8  -> 32 out        */ \
    VMC(8); SCHED0;                    /* retire B16 + c0      */ \
    PCVTW(arP, bb, 0); \
    PGLD(arP, 2, t_);                  /* -> 16 out            */ \
    VMC(8); SCHED0;                    /* retire c1            */ \
    PCVTW(arQ, bb, 1); \
    PGLD(arQ, 3, t_);                  /* -> 16 out            */ \
    VMC(8); SCHED0;                    /* retire c2            */ \
    PCVTW(arP, bb, 2); \
    VMC(0); SCHED0;                    /* retire c3            */ \
    PCVTW(arQ, bb, 3); \
    LGKM0; } while (0)

        PSTAGE(0, 0);            // tile 0 -> buf 0
        BARRIER;

#pragma unroll 1
        for (int u = 0; u < NT; ++u) {
            if (u + 1 < NT) PSTAGE((u + 1) & 1, u + 1);
            BARRIER;
        }
    }
}

// ---------------- naive fp32 fallback (only if ws too small) ----------------
__global__ __launch_bounds__(256) void gemm_naive(const float* __restrict__ x,
                                                  const float* __restrict__ w,
                                                  const float* __restrict__ bias,
                                                  float* __restrict__ out) {
    long o = (long)blockIdx.x * 256 + threadIdx.x;
    if (o >= (long)MDIM * NDIM) return;
    int b = (int)(o / NDIM), n = (int)(o % NDIM);
    const float* xr = x + (long)b * KDIM;
    const float* wr = w + (long)n * KDIM;
    float s = 0.f;
    for (int k = 0; k < KDIM; ++k) s += xr[k] * wr[k];
    out[o] = s + bias[n];
}

extern "C" void kernel_launch(void* const* d_in, const int* in_sizes, int n_in,
                              void* d_out, int out_size, void* d_ws, size_t ws_size,
                              hipStream_t stream) {
    const float* x    = (const float*)d_in[0];
    const float* w    = (const float*)d_in[1];
    const float* bias = (const float*)d_in[2];
    float* out = (float*)d_out;

    const size_t need = (size_t)NDIM * KDIM * sizeof(ushort);   // 2 MiB (W only)
    if (ws_size >= need) {
        ushort* wb = (ushort*)d_ws;
        const int n8w = NDIM * KDIM / 8;   // 131,072
        cvt_f32_bf16<<<n8w / 256, 256, 0, stream>>>(w, wb, n8w);
        dim3 grid(NDIM / BN, MDIM / BM);   // (4, 64) = 256 blocks
        gemm_pc<<<grid, 640, 0, stream>>>(x, wb, bias, out);
    } else {
        const long total = (long)MDIM * NDIM;
        gemm_naive<<<(int)((total + 255) / 256), 256, 0, stream>>>(x, w, bias, out);
    }
}

// Round 14
// 50.263 us; speedup vs baseline: 1.9621x; 1.7358x over previous
//
#include <hip/hip_runtime.h>
#include <hip/hip_bf16.h>
#include <stdint.h>

#define MDIM 16384
#define NDIM 1024
#define KDIM 1024
#define BM 256
#define BN 256
#define BK 64
#define NT (KDIM / BK)   // 16 K-tiles

typedef __bf16 bf16x8 __attribute__((ext_vector_type(8)));
typedef float f32x4 __attribute__((ext_vector_type(4)));
typedef uint  u32x4 __attribute__((ext_vector_type(4)));

#define GLOBAL_CPTR(p) ((const __attribute__((address_space(1))) void*)(p))
#define LDS_PTR(p)     ((__attribute__((address_space(3))) void*)(p))

// ---------------- fp32 -> bf16 (RNE) convert (used for W only) --------------
__device__ inline ushort f2bf_rne(float f) {
    union { float f; uint32_t u; } c; c.f = f;
    uint32_t u = c.u;
    return (ushort)((u + 0x7fffu + ((u >> 16) & 1u)) >> 16);
}

__global__ __launch_bounds__(256) void cvt_f32_bf16(const float* __restrict__ src,
                                                    ushort* __restrict__ dst, int n8) {
    int i = blockIdx.x * 256 + threadIdx.x;
    if (i >= n8) return;
    const float4* s4 = (const float4*)src;
    float4 a = s4[2 * i];
    float4 b = s4[2 * i + 1];
    union { ushort us[8]; uint4 u4; } p;
    p.us[0] = f2bf_rne(a.x); p.us[1] = f2bf_rne(a.y);
    p.us[2] = f2bf_rne(a.z); p.us[3] = f2bf_rne(a.w);
    p.us[4] = f2bf_rne(b.x); p.us[5] = f2bf_rne(b.y);
    p.us[6] = f2bf_rne(b.z); p.us[7] = f2bf_rne(b.w);
    ((uint4*)dst)[i] = p.u4;
}

__device__ inline uint pk2bf(float lo, float hi) {
    union { __hip_bfloat162 h2; uint u; } c;
    c.h2 = __float22bfloat162_rn(float2{lo, hi});
    return c.u;
}

// ---------------- fused 256x256 GEMM, 1 barrier/tile, DE-PINNED --------------
// C = A(MxK, fp32) * B^T (B = W bf16, NxK) + bias.   R7 structure, but the
// staging waits are REGISTER-TIED (dependency-carried) instead of SCHED0-
// fenced, so ds_reads and MFMAs interleave freely with the staging stream.
// Hazard audit:
//  - GLD4 asm defs ar -> VMCA(4) asm "+v" ar -> CVTW reads ar : data-dep chain.
//  - CVTW ds_writes -> LGKM0 ("memory") -> s_barrier asm ("memory"): my writes
//    complete & visible before any wave crosses; next tile's reads can't hoist
//    above the barrier (memory clobber).
//  - B gload_lds (u+1) retired by VMC(8) before tile-end barrier.
//  - Writes go to buf^1 only; reads from buf; all cross-tile WAR/RAW separated
//    by the single tile-end barrier + LGKM0 (reads drained pre-barrier).
__global__ __launch_bounds__(512, 2) void gemm_dp(const float* __restrict__ A,
                                                  const ushort* __restrict__ B,
                                                  const float* __restrict__ bias,
                                                  float* __restrict__ C) {
    __shared__ ushort As[2][BM * BK];   // 2 x 32 KiB
    __shared__ ushort Bs[2][BN * BK];   // 2 x 32 KiB

    const int tid  = threadIdx.x;
    const int lane = tid & 63;
    const int wave = tid >> 6;
    const int wr   = wave >> 2;   // 0..1 : M half (128 rows)
    const int wc   = wave & 3;    // 0..3 : N quarter (64 cols)
    const int l15  = lane & 15;
    const int l4   = lane >> 4;

    // T1: chunked XCD swizzle (bijective, 256 blocks % 8 == 0)
    const int lin  = blockIdx.y * gridDim.x + blockIdx.x;   // 0..255
    const int swz  = (lin & 7) * 32 + (lin >> 3);
    const int brow = (swz >> 2) * BM;
    const int bcol = (swz & 3) * BN;

    // ---- A staging geometry (512 threads cover 256x64 fp32 in 8 GLD4)
    const int lrow = tid >> 3;           // 0..63
    const int lcb  = (tid & 7) * 16;     // byte col (pre-swizzle) in bf16 row
    const int swb  = (lrow & 7) << 4;
    const int wb0  = lrow * 128 + (lcb ^ swb);   // swizzled ds_write byte off
    const float* Ag = A + (size_t)(brow + lrow) * KDIM + (tid & 7) * 8;

    // ---- B staging: global_load_lds linear dest, inverse-swizzled source
    const ushort* Bsrc = B + (size_t)(bcol + lrow) * KDIM + ((lcb ^ swb) >> 1);

    // ---- fragment ds_read byte offsets (swizzled)
    const int sw   = (l15 & 7) << 4;
    const int off0 = l15 * 128 + ((l4 * 16) ^ sw);
    const int off1 = l15 * 128 + (((l4 * 16) + 64) ^ sw);

#define BARRIER asm volatile("s_barrier" ::: "memory")
#define LGKM0  asm volatile("s_waitcnt lgkmcnt(0)" ::: "memory")
#define VMC(n) asm volatile("s_waitcnt vmcnt(" #n ")" ::: "memory")
#define GLD4(d, p) asm volatile("global_load_dwordx4 %0, %1, off" : "=v"(d) : "v"(p) : "memory")
// register-tied counted wait: orders ONLY the ar[] consumers; no sched fence
#define VMCA(n) asm volatile("s_waitcnt vmcnt(" #n ")" \
    : "+v"(ar[0]), "+v"(ar[1]), "+v"(ar[2]), "+v"(ar[3]), \
      "+v"(ar[4]), "+v"(ar[5]), "+v"(ar[6]), "+v"(ar[7]))

    // B tile 256x64 bf16 = 32 KiB staged in 4 global_load_lds issues
#define STG_B4(bb, t_) do { _Pragma("unroll") \
    for (int s_ = 0; s_ < 4; ++s_) \
        __builtin_amdgcn_global_load_lds( \
            GLOBAL_CPTR(Bsrc + (size_t)(s_ * 64) * KDIM + (t_) * BK), \
            LDS_PTR(&Bs[bb][s_ * 4096 + tid * 8]), 16, 0, 0); } while (0)

    // issue all 8 A-loads (256 rows x BK fp32) for K-tile t_ into ar[0..7]
#define GLDA_T(t_) do { \
    const float* q_ = Ag + (size_t)(t_) * BK; \
    GLD4(ar[0], q_);                       GLD4(ar[1], q_ + 4); \
    GLD4(ar[2], q_ + (size_t) 64 * KDIM);  GLD4(ar[3], q_ + (size_t) 64 * KDIM + 4); \
    GLD4(ar[4], q_ + (size_t)128 * KDIM);  GLD4(ar[5], q_ + (size_t)128 * KDIM + 4); \
    GLD4(ar[6], q_ + (size_t)192 * KDIM);  GLD4(ar[7], q_ + (size_t)192 * KDIM + 4); } while (0)

    // convert ar[0..7] and ds_write (swizzled) the full 256-row A tile
#define CVTW_T(bb) do { _Pragma("unroll") \
    for (int h_ = 0; h_ < 4; ++h_) { \
        u32x4 k_; \
        k_.x = pk2bf(ar[2*h_].x, ar[2*h_].y); k_.y = pk2bf(ar[2*h_].z, ar[2*h_].w); \
        k_.z = pk2bf(ar[2*h_+1].x, ar[2*h_+1].y); k_.w = pk2bf(ar[2*h_+1].z, ar[2*h_+1].w); \
        *(u32x4*)((char*)&As[bb][0] + h_ * 64 * 128 + wb0) = k_; } } while (0)

    // ds_read one A m-half (8 x b128) into af
#define LOAD_A(bb, mh) do { _Pragma("unroll") \
    for (int i_ = 0; i_ < 4; ++i_) { \
        const char* pb_ = (const char*)&As[bb][0] + (wr * 128 + (mh) * 64 + i_ * 16) * 128; \
        af[i_][0] = *(const bf16x8*)(pb_ + off0); \
        af[i_][1] = *(const bf16x8*)(pb_ + off1); } } while (0)

    // ds_read ALL B frags (both n-halves, 8 x b128) into bfr
#define LOAD_B_ALL(bb) do { _Pragma("unroll") \
    for (int nh_ = 0; nh_ < 2; ++nh_) { _Pragma("unroll") \
        for (int j_ = 0; j_ < 2; ++j_) { \
            const char* pb_ = (const char*)&Bs[bb][0] + (wc * 64 + nh_ * 32 + j_ * 16) * 128; \
            bfr[nh_][j_][0] = *(const bf16x8*)(pb_ + off0); \
            bfr[nh_][j_][1] = *(const bf16x8*)(pb_ + off1); } } } while (0)

    // 32 MFMA: both n-halves for m-half mh
#define MFMA_H(mh) do { __builtin_amdgcn_s_setprio(1); _Pragma("unroll") \
    for (int i_ = 0; i_ < 4; ++i_) { _Pragma("unroll") \
        for (int nh_ = 0; nh_ < 2; ++nh_) { _Pragma("unroll") \
            for (int j_ = 0; j_ < 2; ++j_) { _Pragma("unroll") \
                for (int kk_ = 0; kk_ < 2; ++kk_) \
                    acc[(mh)*4 + i_][nh_*2 + j_] = __builtin_amdgcn_mfma_f32_16x16x32_bf16( \
                        af[i_][kk_], bfr[nh_][j_][kk_], \
                        acc[(mh)*4 + i_][nh_*2 + j_], 0, 0, 0); } } } \
    __builtin_amdgcn_s_setprio(0); } while (0)

    f32x4  acc[8][4] = {};   // 128 AGPR
    bf16x8 af[4][2];         // 32 VGPR  A frags (current m-half, reloaded)
    bf16x8 bfr[2][2][2];     // 32 VGPR  B frags (whole tile)
    f32x4  ar[8];            // 32 VGPR  A reg-staging

    // ---- prologue: As[0]/Bs[0] staged; leave A(1)x8 in flight.
    GLDA_T(0);                 // A0 x8
    STG_B4(0, 0);              // +B0 x4 = 12
    VMCA(4);                   // retire A0 (B0 stays); dep-carried to CVTW
    CVTW_T(0);
    GLDA_T(1);                 // +A1 x8 -> [B0 x4, A1 x8]
    VMC(8);                    // retire B0 (A1 stays)
    LGKM0;
    BARRIER;                   // invariant: outstanding = A(u+1) x8

    // ---- main loop: ONE barrier per K-tile; counted, dependency-tied waits.
#pragma unroll 1
    for (int u = 0; u < NT; ++u) {
        const int cur = u & 1;
        LOAD_A(cur, 0);                          // 8 ds_read_b128
        LOAD_B_ALL(cur);                         // 8 ds_read_b128
        MFMA_H(0);                               // 32 MFMA (free to interleave)
        LOAD_A(cur, 1);                          // 8 ds_read_b128
        if (u + 1 < NT) {
            STG_B4(cur ^ 1, u + 1);              // [A(u+1)x8, Bx4]
            VMCA(4);                             // retire A(u+1)x8 (dep-tied)
            CVTW_T(cur ^ 1);                     // cvt + swizzled ds_write
        }
        if (u + 2 < NT) GLDA_T(u + 2);           // [Bx4, A(u+2)x8]
        MFMA_H(1);                               // 32 MFMA (free to interleave)
        if (u + 2 < NT)      { VMC(8); }         // retire B(u+1)x4
        else if (u + 1 < NT) { VMC(0); }
        if (u + 1 < NT) { LGKM0; BARRIER; }
    }

    // ---- epilogue: C = acc + bias
#pragma unroll
    for (int mh = 0; mh < 2; ++mh)
#pragma unroll
        for (int i = 0; i < 4; ++i)
#pragma unroll
            for (int nh = 0; nh < 2; ++nh)
#pragma unroll
                for (int j = 0; j < 2; ++j) {
                    f32x4 v = acc[mh * 4 + i][nh * 2 + j];
                    const int row0 = brow + wr * 128 + mh * 64 + i * 16 + l4 * 4;
                    const int col  = bcol + wc * 64 + nh * 32 + j * 16 + l15;
                    const float bb2 = bias[col];
#pragma unroll
                    for (int r = 0; r < 4; ++r)
                        C[(size_t)(row0 + r) * NDIM + col] = v[r] + bb2;
                }
}

// ---------------- naive fp32 fallback (only if ws too small) ----------------
__global__ __launch_bounds__(256) void gemm_naive(const float* __restrict__ x,
                                                  const float* __restrict__ w,
                                                  const float* __restrict__ bias,
                                                  float* __restrict__ out) {
    long o = (long)blockIdx.x * 256 + threadIdx.x;
    if (o >= (long)MDIM * NDIM) return;
    int b = (int)(o / NDIM), n = (int)(o % NDIM);
    const float* xr = x + (long)b * KDIM;
    const float* wr = w + (long)n * KDIM;
    float s = 0.f;
    for (int k = 0; k < KDIM; ++k) s += xr[k] * wr[k];
    out[o] = s + bias[n];
}

extern "C" void kernel_launch(void* const* d_in, const int* in_sizes, int n_in,
                              void* d_out, int out_size, void* d_ws, size_t ws_size,
                              hipStream_t stream) {
    const float* x    = (const float*)d_in[0];
    const float* w    = (const float*)d_in[1];
    const float* bias = (const float*)d_in[2];
    float* out = (float*)d_out;

    const size_t need = (size_t)NDIM * KDIM * sizeof(ushort);   // 2 MiB (W only)
    if (ws_size >= need) {
        ushort* wb = (ushort*)d_ws;
        const int n8w = NDIM * KDIM / 8;   // 131,072
        cvt_f32_bf16<<<n8w / 256, 256, 0, stream>>>(w, wb, n8w);
        dim3 grid(NDIM / BN, MDIM / BM);   // (4, 64) = 256 blocks
        gemm_dp<<<grid, 512, 0, stream>>>(x, wb, bias, out);
    } else {
        const long total = (long)MDIM * NDIM;
        gemm_naive<<<(int)((total + 255) / 256), 256, 0, stream>>>(x, w, bias, out);
    }
}